// Round 1
// baseline (175.426 us; speedup 1.0000x reference)
//
#include <hip/hip_runtime.h>

// Problem constants (fixed by the reference)
#define NUM_LOC   100000
#define EMB_D     256
#define NCLUST    50
#define NTOK      12800   // B*L = 64*200
#define OUT_D     384     // 256 + 128

// True vector types so __builtin_nontemporal_{load,store} accept them
// (HIP float4 is a struct; clang's builtin needs a scalar/vector type).
typedef float f32x4 __attribute__((ext_vector_type(4)));
typedef float f32x2 __attribute__((ext_vector_type(2)));

// One wave (64 lanes) per token; 4 waves (256 threads) per block.
// grid = NTOK/4 = 3200 blocks. No LDS, no barrier: cluster_table (25.6 KB
// total) is L1-resident, so staging it per-block only cost occupancy
// (25.6 KB LDS/block capped us at 6 blocks/CU; now wave-slot-limited at 8).
__global__ __launch_bounds__(256)
void hle_kernel(const int*   __restrict__ loc_ids,        // (B,L) int32
                const float* __restrict__ loc_table,      // (NUM_LOC,256) f32
                const float* __restrict__ cluster_table,  // (50,128) f32
                const float* __restrict__ W_lc,           // (50,NUM_LOC) f32
                const float* __restrict__ b_lc,           // (50,) f32
                float*       __restrict__ out)            // f32 (NTOK,384)
{
    const int tid   = threadIdx.x;
    const int wave  = tid >> 6;
    const int lane  = tid & 63;
    // wave-uniform token index -> scalar load path for the id
    const int token = __builtin_amdgcn_readfirstlane(blockIdx.x * 4 + wave);
    const int id    = loc_ids[token];

    // --- critical path FIRST: W_lc column gather (softmax depends on it).
    //     50 scattered 4B loads (one per lane), ~one 64B line each.
    float logit = -INFINITY;
    if (lane < NCLUST)
        logit = W_lc[(size_t)lane * NUM_LOC + id] + b_lc[lane];

    // --- fine-row gather: independent of everything until the final store.
    //     Nontemporal: rows are effectively single-use (12800 draws from
    //     100000 ids), keep them out of the L2 that W_lc wants.
    const f32x4* fsrc = (const f32x4*)(loc_table + (size_t)id * EMB_D);
    f32x4 fine = __builtin_nontemporal_load(fsrc + lane);

    // --- softmax across the wave (lanes >= 50 hold -inf / contribute 0) ---
    float m = logit;
    #pragma unroll
    for (int off = 32; off > 0; off >>= 1)
        m = fmaxf(m, __shfl_xor(m, off, 64));

    float e = (lane < NCLUST) ? __expf(logit - m) : 0.0f;

    float s = e;
    #pragma unroll
    for (int off = 32; off > 0; off >>= 1)
        s += __shfl_xor(s, off, 64);

    const float w = e * __builtin_amdgcn_rcpf(s);   // lane c holds w[c]

    // --- coarse[d] = sum_c w[c] * ct[c][d]; lane handles d=2*lane, 2*lane+1.
    //     cluster_table read straight from global: 25.6 KB total, L1-hit
    //     after first touch. Unroll 10 => ~10 independent 8B loads in
    //     flight without blowing the <=64-VGPR budget (8 waves/SIMD).
    float acc0 = 0.0f, acc1 = 0.0f;
    const f32x2* ct2 = (const f32x2*)cluster_table;
    #pragma unroll 10
    for (int c = 0; c < NCLUST; ++c) {
        float wc = __shfl(w, c, 64);       // uniform src lane -> readlane
        f32x2 v = ct2[c * 64 + lane];
        acc0 = __builtin_fmaf(wc, v.x, acc0);
        acc1 = __builtin_fmaf(wc, v.y, acc1);
    }

    // --- write output row [fine(256) | coarse(128)], nontemporal:
    //     out is never re-read by this kernel; don't write-allocate in L2.
    float* orow = out + (size_t)token * OUT_D;
    __builtin_nontemporal_store(fine, (f32x4*)orow + lane);          // 0..1023
    f32x2 cw = { acc0, acc1 };
    __builtin_nontemporal_store(cw, (f32x2*)(orow + EMB_D) + lane);  // 1024..1535
}

extern "C" void kernel_launch(void* const* d_in, const int* in_sizes, int n_in,
                              void* d_out, int out_size, void* d_ws, size_t ws_size,
                              hipStream_t stream) {
    const int*   loc_ids       = (const int*)d_in[0];
    const float* loc_table     = (const float*)d_in[1];
    const float* cluster_table = (const float*)d_in[2];
    const float* W_lc          = (const float*)d_in[3];
    const float* b_lc          = (const float*)d_in[4];
    float*       out           = (float*)d_out;

    hle_kernel<<<NTOK / 4, 256, 0, stream>>>(loc_ids, loc_table, cluster_table,
                                             W_lc, b_lc, out);
}

// Round 2
// 171.043 us; speedup vs baseline: 1.0256x; 1.0256x over previous
//
#include <hip/hip_runtime.h>

// Problem constants (fixed by the reference)
#define NUM_LOC   100000
#define EMB_D     256
#define NCLUST    50
#define NTOK      12800   // B*L = 64*200
#define OUT_D     384     // 256 + 128
#define TPB       8       // tokens (waves) per block -> 512 threads

// One wave (64 lanes) per token; 8 waves (512 threads) per block.
// grid = NTOK/8 = 1600 blocks.
// Occupancy: 512-thr blocks, 25.6 KB LDS -> LDS allows 6 blocks/CU,
// wave slots allow 4 -> wave-bound at 4 blocks/CU = 32 waves/CU (FULL,
// vs 24/32 for the 256-thread round-0 config).
__global__ __launch_bounds__(512)
void hle_kernel(const int*   __restrict__ loc_ids,        // (B,L) int32
                const float* __restrict__ loc_table,      // (NUM_LOC,256) f32
                const float* __restrict__ cluster_table,  // (50,128) f32
                const float* __restrict__ W_lc,           // (50,NUM_LOC) f32
                const float* __restrict__ b_lc,           // (50,) f32
                float*       __restrict__ out)            // f32 (NTOK,384)
{
    // cluster_table staged in LDS: 50*128*4 = 25.6 KB (coarse loop runs on
    // the LDS pipe, keeping the VMEM pipe free for the gathers).
    __shared__ float s_ct[NCLUST * 128];

    const int tid  = threadIdx.x;
    const int wave = tid >> 6;
    const int lane = tid & 63;
    // wave-uniform token -> scalar (s_load) path for the id
    const int token = __builtin_amdgcn_readfirstlane(blockIdx.x * TPB + wave);
    const int id    = loc_ids[token];

    // --- issue ALL dependent gathers BEFORE the staging barrier, so the
    //     barrier's vmcnt(0) drain overlaps their HBM latency instead of
    //     the chain paying a full round-trip after the barrier. ---

    // W_lc column gather (the softmax critical path): 50 scattered 4B loads.
    float logit = -INFINITY;
    if (lane < NCLUST)
        logit = W_lc[(unsigned)lane * (unsigned)NUM_LOC + (unsigned)id]
                + b_lc[lane];

    // fine-row gather: 4 f32 per lane = whole 256-row per wave.
    const float4* fsrc = (const float4*)(loc_table + (size_t)id * EMB_D);
    float4 fine = fsrc[lane];

    // --- stage cluster_table into LDS as float4 (1600 float4 / 512 thr) ---
    {
        const float4* src = (const float4*)cluster_table;
        float4* dst = (float4*)s_ct;
        for (int i = tid; i < NCLUST * 32; i += 512)
            dst[i] = src[i];
    }
    __syncthreads();   // drains staging AND the in-flight gathers together

    // --- softmax across the wave (lanes >= 50 hold -inf / contribute 0) ---
    float m = logit;
    #pragma unroll
    for (int off = 32; off > 0; off >>= 1)
        m = fmaxf(m, __shfl_xor(m, off, 64));

    float e = (lane < NCLUST) ? __expf(logit - m) : 0.0f;

    float s = e;
    #pragma unroll
    for (int off = 32; off > 0; off >>= 1)
        s += __shfl_xor(s, off, 64);

    const float w = e / s;                     // lane c holds w[c]

    // --- coarse[d] = sum_c w[c]*ct[c][d]; lane handles d=2*lane, 2*lane+1.
    //     ds_read_b64, consecutive lanes -> consecutive 8B: 2-way bank
    //     mode, conflict-free. ---
    float acc0 = 0.0f, acc1 = 0.0f;
    const float2* ct2 = (const float2*)s_ct;
    #pragma unroll 10
    for (int c = 0; c < NCLUST; ++c) {
        float wc = __shfl(w, c, 64);           // uniform src lane -> readlane
        float2 v = ct2[c * 64 + lane];
        acc0 = fmaf(wc, v.x, acc0);
        acc1 = fmaf(wc, v.y, acc1);
    }

    // --- write output row [fine(256) | coarse(128)], plain cached stores ---
    float* orow = out + (size_t)token * OUT_D;
    ((float4*)orow)[lane] = fine;              // bytes 0..1023, coalesced
    float2 cw = make_float2(acc0, acc1);
    ((float2*)(orow + EMB_D))[lane] = cw;      // bytes 1024..1535, coalesced
}

extern "C" void kernel_launch(void* const* d_in, const int* in_sizes, int n_in,
                              void* d_out, int out_size, void* d_ws, size_t ws_size,
                              hipStream_t stream) {
    const int*   loc_ids       = (const int*)d_in[0];
    const float* loc_table     = (const float*)d_in[1];
    const float* cluster_table = (const float*)d_in[2];
    const float* W_lc          = (const float*)d_in[3];
    const float* b_lc          = (const float*)d_in[4];
    float*       out           = (float*)d_out;

    hle_kernel<<<NTOK / TPB, 512, 0, stream>>>(loc_ids, loc_table, cluster_table,
                                               W_lc, b_lc, out);
}